// Round 10
// baseline (139.750 us; speedup 1.0000x reference)
//
#include <hip/hip_runtime.h>
#include <hip/hip_bf16.h>
#include <stdint.h>

#define B_ 4
#define S_ 2048
#define D_ 512
#define H_ 8
#define HD_ 64
#define M_ (B_*S_)   // 8192

typedef __bf16 bf16x8 __attribute__((ext_vector_type(8)));
typedef float f32x4 __attribute__((ext_vector_type(4)));
typedef float f32x16 __attribute__((ext_vector_type(16)));

__device__ __forceinline__ unsigned short f2b(float f) {
  union { float f; unsigned u; } v; v.f = f;
  unsigned r = v.u + 0x7fff + ((v.u >> 16) & 1);
  return (unsigned short)(r >> 16);
}

__device__ __forceinline__ float exp2_hw(float x) {
  return __builtin_amdgcn_exp2f(x);  // v_exp_f32: D = 2^S0
}

__device__ __forceinline__ unsigned cvtpk_bf16(float lo, float hi) {
  unsigned r;
  asm("v_cvt_pk_bf16_f32 %0, %1, %2" : "=v"(r) : "v"(lo), "v"(hi));
  return r;
}

// vdst' = {vdst.lo, vsrc.lo}; vsrc' = {vdst.hi, vsrc.hi}
__device__ __forceinline__ void plswap(unsigned &a, unsigned &b) {
  asm volatile("v_permlane32_swap_b32 %0, %1" : "+v"(a), "+v"(b));
}

__device__ __forceinline__ void gload16(const void* g, void* lds) {
  __builtin_amdgcn_global_load_lds(
      (const __attribute__((address_space(1))) unsigned int*)g,
      (__attribute__((address_space(3))) unsigned int*)lds, 16, 0, 0);
}

// ---------------- f32 -> bf16 conversion (x + all 4 weights, one launch) ----------------
#define XN4 (M_ * D_ / 4)
#define WN4 (D_ * D_ / 4)
__global__ __launch_bounds__(256) void cvt_all_kernel(const float* __restrict__ x,
    const float* __restrict__ wq, const float* __restrict__ wk,
    const float* __restrict__ wv, const float* __restrict__ wo,
    unsigned short* __restrict__ xb, unsigned short* __restrict__ wqb,
    unsigned short* __restrict__ wkb, unsigned short* __restrict__ wvb,
    unsigned short* __restrict__ wob) {
  int i = blockIdx.x * blockDim.x + threadIdx.x;
  const float* src; unsigned short* dst; int off;
  if (i < XN4) { src = x; dst = xb; off = i; }
  else {
    int j = i - XN4;
    int sel = j / WN4; off = j - sel * WN4;
    src = (sel == 0) ? wq : (sel == 1) ? wk : (sel == 2) ? wv : wo;
    dst = (sel == 0) ? wqb : (sel == 1) ? wkb : (sel == 2) ? wvb : wob;
  }
  float4 v = ((const float4*)src)[off];
  ushort4 o;
  o.x = f2b(v.x); o.y = f2b(v.y); o.z = f2b(v.z); o.w = f2b(v.w);
  ((ushort4*)dst)[off] = o;
}

// ---------------- GEMM core: C[128x128] = A[128xK] * B^T (B is [N][K]) ----------------
__device__ __forceinline__ void gemm_core(const unsigned short* __restrict__ A,
                                          const unsigned short* __restrict__ W,
                                          int m0, int n0, f32x4 (&acc)[4][4],
                                          unsigned short* As, unsigned short* Bs) {
  int tid = threadIdx.x;
  int w = tid >> 6, lane = tid & 63;
  int l15 = lane & 15, g = lane >> 4;
  int wr = w >> 1, wc = w & 1;
  for (int k0 = 0; k0 < D_; k0 += 64) {
    #pragma unroll
    for (int i = 0; i < 4; ++i) {
      int l = i * 256 + w * 64 + lane;
      int row = l >> 3, seg = l & 7;
      int sseg = seg ^ (row & 7);
      gload16(A + (size_t)(m0 + row) * D_ + k0 + sseg * 8,
              (char*)As + (size_t)(i * 256 + w * 64) * 16);
      gload16(W + (size_t)(n0 + row) * D_ + k0 + sseg * 8,
              (char*)Bs + (size_t)(i * 256 + w * 64) * 16);
    }
    __syncthreads();
    #pragma unroll
    for (int kk = 0; kk < 2; ++kk) {
      int sw = ((kk * 4 + g) ^ (l15 & 7)) * 8;
      bf16x8 af[4], bfr[4];
      #pragma unroll
      for (int t = 0; t < 4; ++t) {
        af[t]  = *(const bf16x8*)&As[(wr * 64 + t * 16 + l15) * 64 + sw];
        bfr[t] = *(const bf16x8*)&Bs[(wc * 64 + t * 16 + l15) * 64 + sw];
      }
      #pragma unroll
      for (int mi = 0; mi < 4; ++mi)
        #pragma unroll
        for (int ni = 0; ni < 4; ++ni)
          acc[mi][ni] = __builtin_amdgcn_mfma_f32_16x16x32_bf16(af[mi], bfr[ni], acc[mi][ni], 0, 0, 0);
    }
    __syncthreads();
  }
}

// ---------------- QKV projection ----------------
__global__ __launch_bounds__(256) void gemm_qkv(const unsigned short* __restrict__ xb,
    const unsigned short* __restrict__ wqb, const unsigned short* __restrict__ wkb,
    const unsigned short* __restrict__ wvb,
    const float* __restrict__ bq, const float* __restrict__ bk, const float* __restrict__ bv,
    unsigned short* __restrict__ Qb, unsigned short* __restrict__ Kb, unsigned short* __restrict__ Vtb) {
  __shared__ unsigned short As[128 * 64], Bs[128 * 64];
  int z = blockIdx.z;
  const unsigned short* W = (z == 0) ? wqb : ((z == 1) ? wkb : wvb);
  const float* bias = (z == 0) ? bq : ((z == 1) ? bk : bv);
  int m0 = blockIdx.x * 128, n0 = blockIdx.y * 128;
  f32x4 zero4 = {0.f, 0.f, 0.f, 0.f};
  f32x4 acc[4][4];
  #pragma unroll
  for (int mi = 0; mi < 4; ++mi)
    #pragma unroll
    for (int ni = 0; ni < 4; ++ni) acc[mi][ni] = zero4;
  gemm_core(xb, W, m0, n0, acc, As, Bs);
  int tid = threadIdx.x;
  int w = tid >> 6, lane = tid & 63, l15 = lane & 15, g = lane >> 4;
  int wr = w >> 1, wc = w & 1;
  #pragma unroll
  for (int mi = 0; mi < 4; ++mi)
    #pragma unroll
    for (int ni = 0; ni < 4; ++ni) {
      int e = n0 + wc * 64 + ni * 16 + l15;
      float bb = bias[e];
      int h = e >> 6, dd = e & 63;
      #pragma unroll
      for (int r = 0; r < 4; ++r) {
        int m = m0 + wr * 64 + mi * 16 + g * 4 + r;
        int b = m >> 11, s = m & 2047;
        unsigned short u = f2b(acc[mi][ni][r] + bb);
        int bh = b * H_ + h;
        if (z == 0)      Qb[((size_t)bh * S_ + s) * HD_ + dd] = u;
        else if (z == 1) Kb[((size_t)bh * S_ + s) * HD_ + dd] = u;
        else             Vtb[((size_t)bh * HD_ + dd) * S_ + s] = u;  // V transposed
      }
    }
}

// ---------------- output projection -> f32 tmp ----------------
__global__ __launch_bounds__(256) void gemm_proj(const unsigned short* __restrict__ AOb,
    const unsigned short* __restrict__ wob, const float* __restrict__ bo, float* __restrict__ Pf) {
  __shared__ unsigned short As[128 * 64], Bs[128 * 64];
  int m0 = blockIdx.x * 128, n0 = blockIdx.y * 128;
  f32x4 zero4 = {0.f, 0.f, 0.f, 0.f};
  f32x4 acc[4][4];
  #pragma unroll
  for (int mi = 0; mi < 4; ++mi)
    #pragma unroll
    for (int ni = 0; ni < 4; ++ni) acc[mi][ni] = zero4;
  gemm_core(AOb, wob, m0, n0, acc, As, Bs);
  int tid = threadIdx.x;
  int w = tid >> 6, lane = tid & 63, l15 = lane & 15, g = lane >> 4;
  int wr = w >> 1, wc = w & 1;
  #pragma unroll
  for (int mi = 0; mi < 4; ++mi)
    #pragma unroll
    for (int ni = 0; ni < 4; ++ni) {
      int e = n0 + wc * 64 + ni * 16 + l15;
      float bb = bo[e];
      #pragma unroll
      for (int r = 0; r < 4; ++r) {
        int m = m0 + wr * 64 + mi * 16 + g * 4 + r;
        Pf[(size_t)m * D_ + e] = acc[mi][ni][r] + bb;
      }
    }
}

// ---- flash attention: swapped QK^T 32x32x16, in-register P, optional split-K over gridDim.z ----
// If Of != nullptr: write f32 partial O and partial row-sum l (no division). Else bf16 O directly.
__global__ __launch_bounds__(256) void attn_kernel(const unsigned short* __restrict__ Qb,
    const unsigned short* __restrict__ Kb, const unsigned short* __restrict__ Vtb,
    const int* __restrict__ mask, const float* __restrict__ tptr,
    unsigned short* __restrict__ AOb, float* __restrict__ Of, float* __restrict__ lsum) {
  __shared__ unsigned short Ks[2][64 * 64], Vs[2][64 * 64];
  int bh = blockIdx.y, b = bh >> 3, h = bh & 7;
  int tid = threadIdx.x, w = tid >> 6, lane = tid & 63;
  int l31 = lane & 31, hi = lane >> 5;
  int ktn = 32 / gridDim.z;
  int kt0 = blockIdx.z * ktn;
  if (Of) {
    Of   += (size_t)blockIdx.z * M_ * D_;
    lsum += (size_t)blockIdx.z * 32 * S_;
  }
  float tl2 = tptr[0] * 1.44269504088896340736f;  // temp * log2(e)
  int q0w = blockIdx.x * 128 + w * 32;
  const unsigned short* Qbase = Qb + (size_t)bh * S_ * HD_;
  const int* mbase = mask + (size_t)b * S_;

  // Q as B-frag (32x32x16): lane n=l31=q, k=hi*8+j; qf[kk] covers d = kk*16 + hi*8 + j
  bf16x8 qf[4];
  #pragma unroll
  for (int kk = 0; kk < 4; ++kk)
    qf[kk] = *(const bf16x8*)&Qbase[(size_t)(q0w + l31) * HD_ + kk * 16 + hi * 8];

  bf16x8 ones;
  #pragma unroll
  for (int j = 0; j < 8; ++j) ones[j] = (__bf16)1.0f;

  f32x16 out[2], lacc;
  #pragma unroll
  for (int i = 0; i < 16; ++i) { out[0][i] = 0.f; out[1][i] = 0.f; lacc[i] = 0.f; }

  #define STAGE_KV(buf, kb_) do {                                              \
    _Pragma("unroll")                                                          \
    for (int i = 0; i < 2; ++i) {                                              \
      int l = i * 256 + w * 64 + lane;                                         \
      int row = l >> 3, seg = l & 7;                                           \
      int sseg = seg ^ (row & 7);                                              \
      gload16(Kb + ((size_t)bh * S_ + (kb_) + row) * HD_ + sseg * 8,           \
              (char*)Ks[buf] + (size_t)(i * 256 + w * 64) * 16);               \
      gload16(Vtb + ((size_t)bh * HD_ + row) * S_ + (kb_) + sseg * 8,          \
              (char*)Vs[buf] + (size_t)(i * 256 + w * 64) * 16);               \
    }                                                                          \
  } while (0)

  int mv;
  STAGE_KV(kt0 & 1, kt0 * 64);
  mv = mbase[kt0 * 64 + lane];
  __syncthreads();

  for (int kt = kt0; kt < kt0 + ktn; ++kt) {
    int cur = kt & 1;
    unsigned long long bm = __ballot(mv != 0);   // bit k = masked(kb + k)
    if (kt < kt0 + ktn - 1) {
      STAGE_KV(cur ^ 1, (kt + 1) * 64);
      mv = mbase[(kt + 1) * 64 + lane];
    }
    // ---- S^T = K . Q^T ----
    f32x16 st[2];
    #pragma unroll
    for (int i = 0; i < 16; ++i) { st[0][i] = 0.f; st[1][i] = 0.f; }
    __builtin_amdgcn_s_setprio(1);
    #pragma unroll
    for (int kk = 0; kk < 4; ++kk) {
      int sw = ((2 * kk + hi) ^ (l31 & 7)) * 8;
      bf16x8 ka0 = *(const bf16x8*)&Ks[cur][l31 * 64 + sw];
      bf16x8 ka1 = *(const bf16x8*)&Ks[cur][(32 + l31) * 64 + sw];
      st[0] = __builtin_amdgcn_mfma_f32_32x32x16_bf16(ka0, qf[kk], st[0], 0, 0, 0);
      st[1] = __builtin_amdgcn_mfma_f32_32x32x16_bf16(ka1, qf[kk], st[1], 0, 0, 0);
    }
    __builtin_amdgcn_s_setprio(0);
    // ---- softmax (static max 0): P = exp2(s*tl2), zero masked k ----
    unsigned shlo = (unsigned)(bm >> (4 * hi));
    unsigned shhi = (unsigned)(bm >> (32 + 4 * hi));
    #pragma unroll
    for (int ktile = 0; ktile < 2; ++ktile)
      #pragma unroll
      for (int reg = 0; reg < 16; ++reg) {
        const int kc = 32 * ktile + (reg & 3) + 8 * (reg >> 2);  // + 4*hi = key index
        float pv = exp2_hw(st[ktile][reg] * tl2);
        unsigned bit = ((kc < 32 ? shlo : shhi) >> (kc & 31)) & 1u;
        st[ktile][reg] = bit ? 0.f : pv;
      }
    // ---- build PV A-frags in-register and accumulate ----
    __builtin_amdgcn_s_setprio(1);
    #pragma unroll
    for (int kp = 0; kp < 4; ++kp) {
      const int kt8 = kp >> 1;
      const int ro = 8 * (kp & 1);
      unsigned Xa = cvtpk_bf16(st[kt8][ro + 0], st[kt8][ro + 1]);
      unsigned Ya = cvtpk_bf16(st[kt8][ro + 4], st[kt8][ro + 5]);
      unsigned Xb = cvtpk_bf16(st[kt8][ro + 2], st[kt8][ro + 3]);
      unsigned Yb = cvtpk_bf16(st[kt8][ro + 6], st[kt8][ro + 7]);
      plswap(Xa, Ya);
      plswap(Xb, Yb);
      union { unsigned u[4]; bf16x8 v; } pu;
      pu.u[0] = Xa; pu.u[1] = Xb; pu.u[2] = Ya; pu.u[3] = Yb;
      bf16x8 pa = pu.v;
      #pragma unroll
      for (int dn = 0; dn < 2; ++dn) {
        int row = dn * 32 + l31;
        bf16x8 vb = *(const bf16x8*)&Vs[cur][row * 64 + ((2 * kp + hi) ^ (row & 7)) * 8];
        out[dn] = __builtin_amdgcn_mfma_f32_32x32x16_bf16(pa, vb, out[dn], 0, 0, 0);
      }
      lacc = __builtin_amdgcn_mfma_f32_32x32x16_bf16(pa, ones, lacc, 0, 0, 0);
    }
    __builtin_amdgcn_s_setprio(0);
    __syncthreads();
  }
  // ---- epilogue ----
  if (Of) {
    #pragma unroll
    for (int reg = 0; reg < 16; ++reg) {
      int q = q0w + (reg & 3) + 8 * (reg >> 2) + 4 * hi;
      #pragma unroll
      for (int dn = 0; dn < 2; ++dn)
        Of[((size_t)b * S_ + q) * D_ + h * HD_ + dn * 32 + l31] = out[dn][reg];
      if (l31 == 0) lsum[(size_t)bh * S_ + q] = lacc[reg];
    }
  } else {
    #pragma unroll
    for (int reg = 0; reg < 16; ++reg) {
      float inv = 1.f / lacc[reg];
      int q = q0w + (reg & 3) + 8 * (reg >> 2) + 4 * hi;
      #pragma unroll
      for (int dn = 0; dn < 2; ++dn)
        AOb[((size_t)b * S_ + q) * D_ + h * HD_ + dn * 32 + l31] = f2b(out[dn][reg] * inv);
    }
  }
  #undef STAGE_KV
}

// ---------------- split-K merge: AOb = (Of0 + Of1) / (l0 + l1), bf16 ----------------
__global__ __launch_bounds__(256) void merge_kernel(const float* __restrict__ Of,
    const float* __restrict__ ls, unsigned short* __restrict__ AOb) {
  const float* Of0 = Of;
  const float* Of1 = Of + (size_t)M_ * D_;
  const float* l0 = ls;
  const float* l1 = ls + (size_t)32 * S_;
  int t = blockIdx.x * 256 + threadIdx.x;
  size_t i8 = (size_t)t * 8;
  int row = t >> 6;                 // 64 threads per 512-wide row
  int col = (t & 63) * 8;
  int b = row >> 11, s = row & 2047, h = col >> 6;
  int bh = b * H_ + h;
  float l = l0[(size_t)bh * S_ + s] + l1[(size_t)bh * S_ + s];
  float inv = 1.f / l;
  float4 a0 = *(const float4*)&Of0[i8];
  float4 a1 = *(const float4*)&Of0[i8 + 4];
  float4 c0 = *(const float4*)&Of1[i8];
  float4 c1 = *(const float4*)&Of1[i8 + 4];
  ushort4 o0, o1;
  o0.x = f2b((a0.x + c0.x) * inv); o0.y = f2b((a0.y + c0.y) * inv);
  o0.z = f2b((a0.z + c0.z) * inv); o0.w = f2b((a0.w + c0.w) * inv);
  o1.x = f2b((a1.x + c1.x) * inv); o1.y = f2b((a1.y + c1.y) * inv);
  o1.z = f2b((a1.z + c1.z) * inv); o1.w = f2b((a1.w + c1.w) * inv);
  *(ushort4*)&AOb[i8] = o0;
  *(ushort4*)&AOb[i8 + 4] = o1;
}

// ---------------- residual + LayerNorm ----------------
__global__ __launch_bounds__(256) void ln_kernel(const float* __restrict__ Pf,
    const float* __restrict__ x, const float* __restrict__ gamma,
    const float* __restrict__ beta, float* __restrict__ out) {
  int row = blockIdx.x * 4 + (threadIdx.x >> 6);
  int lane = threadIdx.x & 63;
  const float* pr = Pf + (size_t)row * D_;
  const float* xr = x + (size_t)row * D_;
  float4 a0 = *(const float4*)(pr + lane * 4);
  float4 a1 = *(const float4*)(pr + 256 + lane * 4);
  float4 b0 = *(const float4*)(xr + lane * 4);
  float4 b1 = *(const float4*)(xr + 256 + lane * 4);
  float y[8] = {a0.x + b0.x, a0.y + b0.y, a0.z + b0.z, a0.w + b0.w,
                a1.x + b1.x, a1.y + b1.y, a1.z + b1.z, a1.w + b1.w};
  float s = 0.f, s2 = 0.f;
  #pragma unroll
  for (int i = 0; i < 8; ++i) { s += y[i]; s2 += y[i] * y[i]; }
  #pragma unroll
  for (int d = 1; d < 64; d <<= 1) { s += __shfl_xor(s, d); s2 += __shfl_xor(s2, d); }
  float mu = s * (1.f / 512.f);
  float var = s2 * (1.f / 512.f) - mu * mu;
  float inv = rsqrtf(fmaxf(var, 0.f) + 1e-6f);
  float4 g0 = *(const float4*)(gamma + lane * 4);
  float4 g1 = *(const float4*)(gamma + 256 + lane * 4);
  float4 e0 = *(const float4*)(beta + lane * 4);
  float4 e1 = *(const float4*)(beta + 256 + lane * 4);
  float* orow = out + (size_t)row * D_;
  float4 o0 = {(y[0] - mu) * inv * g0.x + e0.x, (y[1] - mu) * inv * g0.y + e0.y,
               (y[2] - mu) * inv * g0.z + e0.z, (y[3] - mu) * inv * g0.w + e0.w};
  float4 o1 = {(y[4] - mu) * inv * g1.x + e1.x, (y[5] - mu) * inv * g1.y + e1.y,
               (y[6] - mu) * inv * g1.z + e1.z, (y[7] - mu) * inv * g1.w + e1.w};
  *(float4*)(orow + lane * 4) = o0;
  *(float4*)(orow + 256 + lane * 4) = o1;
}

extern "C" void kernel_launch(void* const* d_in, const int* in_sizes, int n_in,
                              void* d_out, int out_size, void* d_ws, size_t ws_size,
                              hipStream_t stream) {
  const float* x = (const float*)d_in[0];
  const int* mask = (const int*)d_in[1];
  const float* wq = (const float*)d_in[2];
  const float* bq = (const float*)d_in[3];
  const float* wk = (const float*)d_in[4];
  const float* bk = (const float*)d_in[5];
  const float* wv = (const float*)d_in[6];
  const float* bv = (const float*)d_in[7];
  const float* wo = (const float*)d_in[8];
  const float* bo = (const float*)d_in[9];
  const float* gamma = (const float*)d_in[10];
  const float* beta = (const float*)d_in[11];
  const float* temp = (const float*)d_in[12];
  float* out = (float*)d_out;
  char* ws = (char*)d_ws;
  const size_t MB = (size_t)1 << 20;
  unsigned short* xb  = (unsigned short*)(ws);                    // 8 MB
  unsigned short* wqb = (unsigned short*)(ws + 8 * MB);           // 0.5 MB
  unsigned short* wkb = (unsigned short*)(ws + 8 * MB + 512 * 1024);
  unsigned short* wvb = (unsigned short*)(ws + 9 * MB);
  unsigned short* wob = (unsigned short*)(ws + 9 * MB + 512 * 1024);
  unsigned short* Qb  = (unsigned short*)(ws + 10 * MB);          // 8 MB
  unsigned short* Kb  = (unsigned short*)(ws + 18 * MB);          // 8 MB
  float*          Pf  = (float*)(ws + 10 * MB);                   // 16 MB, overlays Q/K (used after attn)
  unsigned short* Vtb = (unsigned short*)(ws + 26 * MB);          // 8 MB
  unsigned short* AOb = (unsigned short*)(ws + 34 * MB);          // 8 MB
  float*          Ofp = (float*)(ws + 42 * MB);                   // 2 x 16 MB partial O
  float*          lsp = (float*)(ws + 74 * MB);                   // 2 x 256 KB partial l

  cvt_all_kernel<<<(XN4 + 4 * WN4 + 255) / 256, 256, 0, stream>>>(
      x, wq, wk, wv, wo, xb, wqb, wkb, wvb, wob);
  gemm_qkv<<<dim3(64, 4, 3), 256, 0, stream>>>(xb, wqb, wkb, wvb, bq, bk, bv, Qb, Kb, Vtb);
  if (ws_size >= 75 * MB) {
    attn_kernel<<<dim3(16, 32, 2), 256, 0, stream>>>(Qb, Kb, Vtb, mask, temp, nullptr, Ofp, lsp);
    merge_kernel<<<M_ * D_ / 2048, 256, 0, stream>>>(Ofp, lsp, AOb);
  } else {
    attn_kernel<<<dim3(16, 32, 1), 256, 0, stream>>>(Qb, Kb, Vtb, mask, temp, AOb, nullptr, nullptr);
  }
  gemm_proj<<<dim3(64, 4), 256, 0, stream>>>(AOb, wob, bo, Pf);
  ln_kernel<<<2048, 256, 0, stream>>>(Pf, x, gamma, beta, out);
}

// Round 11
// 124.928 us; speedup vs baseline: 1.1186x; 1.1186x over previous
//
#include <hip/hip_runtime.h>
#include <hip/hip_bf16.h>
#include <stdint.h>

#define B_ 4
#define S_ 2048
#define D_ 512
#define H_ 8
#define HD_ 64
#define M_ (B_*S_)   // 8192

typedef __bf16 bf16x8 __attribute__((ext_vector_type(8)));
typedef float f32x4 __attribute__((ext_vector_type(4)));
typedef float f32x16 __attribute__((ext_vector_type(16)));

__device__ __forceinline__ unsigned short f2b(float f) {
  union { float f; unsigned u; } v; v.f = f;
  unsigned r = v.u + 0x7fff + ((v.u >> 16) & 1);
  return (unsigned short)(r >> 16);
}

__device__ __forceinline__ float exp2_hw(float x) {
  return __builtin_amdgcn_exp2f(x);  // v_exp_f32: D = 2^S0
}

__device__ __forceinline__ unsigned cvtpk_bf16(float lo, float hi) {
  unsigned r;
  asm("v_cvt_pk_bf16_f32 %0, %1, %2" : "=v"(r) : "v"(lo), "v"(hi));
  return r;
}

// vdst' = {vdst.lo, vsrc.lo}; vsrc' = {vdst.hi, vsrc.hi}
__device__ __forceinline__ void plswap(unsigned &a, unsigned &b) {
  asm volatile("v_permlane32_swap_b32 %0, %1" : "+v"(a), "+v"(b));
}

__device__ __forceinline__ void gload16(const void* g, void* lds) {
  __builtin_amdgcn_global_load_lds(
      (const __attribute__((address_space(1))) unsigned int*)g,
      (__attribute__((address_space(3))) unsigned int*)lds, 16, 0, 0);
}

// ---------------- f32 -> bf16 conversion (x + all 4 weights, one launch) ----------------
#define XN4 (M_ * D_ / 4)
#define WN4 (D_ * D_ / 4)
__global__ __launch_bounds__(256) void cvt_all_kernel(const float* __restrict__ x,
    const float* __restrict__ wq, const float* __restrict__ wk,
    const float* __restrict__ wv, const float* __restrict__ wo,
    unsigned short* __restrict__ xb, unsigned short* __restrict__ wqb,
    unsigned short* __restrict__ wkb, unsigned short* __restrict__ wvb,
    unsigned short* __restrict__ wob) {
  int i = blockIdx.x * blockDim.x + threadIdx.x;
  const float* src; unsigned short* dst; int off;
  if (i < XN4) { src = x; dst = xb; off = i; }
  else {
    int j = i - XN4;
    int sel = j / WN4; off = j - sel * WN4;
    src = (sel == 0) ? wq : (sel == 1) ? wk : (sel == 2) ? wv : wo;
    dst = (sel == 0) ? wqb : (sel == 1) ? wkb : (sel == 2) ? wvb : wob;
  }
  float4 v = ((const float4*)src)[off];
  ushort4 o;
  o.x = f2b(v.x); o.y = f2b(v.y); o.z = f2b(v.z); o.w = f2b(v.w);
  ((ushort4*)dst)[off] = o;
}

// ---------------- GEMM core: C[128x128] = A[128xK] * B^T (B is [N][K]) ----------------
__device__ __forceinline__ void gemm_core(const unsigned short* __restrict__ A,
                                          const unsigned short* __restrict__ W,
                                          int m0, int n0, f32x4 (&acc)[4][4],
                                          unsigned short* As, unsigned short* Bs) {
  int tid = threadIdx.x;
  int w = tid >> 6, lane = tid & 63;
  int l15 = lane & 15, g = lane >> 4;
  int wr = w >> 1, wc = w & 1;
  for (int k0 = 0; k0 < D_; k0 += 64) {
    #pragma unroll
    for (int i = 0; i < 4; ++i) {
      int l = i * 256 + w * 64 + lane;
      int row = l >> 3, seg = l & 7;
      int sseg = seg ^ (row & 7);
      gload16(A + (size_t)(m0 + row) * D_ + k0 + sseg * 8,
              (char*)As + (size_t)(i * 256 + w * 64) * 16);
      gload16(W + (size_t)(n0 + row) * D_ + k0 + sseg * 8,
              (char*)Bs + (size_t)(i * 256 + w * 64) * 16);
    }
    __syncthreads();
    #pragma unroll
    for (int kk = 0; kk < 2; ++kk) {
      int sw = ((kk * 4 + g) ^ (l15 & 7)) * 8;
      bf16x8 af[4], bfr[4];
      #pragma unroll
      for (int t = 0; t < 4; ++t) {
        af[t]  = *(const bf16x8*)&As[(wr * 64 + t * 16 + l15) * 64 + sw];
        bfr[t] = *(const bf16x8*)&Bs[(wc * 64 + t * 16 + l15) * 64 + sw];
      }
      #pragma unroll
      for (int mi = 0; mi < 4; ++mi)
        #pragma unroll
        for (int ni = 0; ni < 4; ++ni)
          acc[mi][ni] = __builtin_amdgcn_mfma_f32_16x16x32_bf16(af[mi], bfr[ni], acc[mi][ni], 0, 0, 0);
    }
    __syncthreads();
  }
}

// ---------------- QKV projection ----------------
__global__ __launch_bounds__(256) void gemm_qkv(const unsigned short* __restrict__ xb,
    const unsigned short* __restrict__ wqb, const unsigned short* __restrict__ wkb,
    const unsigned short* __restrict__ wvb,
    const float* __restrict__ bq, const float* __restrict__ bk, const float* __restrict__ bv,
    unsigned short* __restrict__ Qb, unsigned short* __restrict__ Kb, unsigned short* __restrict__ Vtb) {
  __shared__ unsigned short As[128 * 64], Bs[128 * 64];
  int z = blockIdx.z;
  const unsigned short* W = (z == 0) ? wqb : ((z == 1) ? wkb : wvb);
  const float* bias = (z == 0) ? bq : ((z == 1) ? bk : bv);
  int m0 = blockIdx.x * 128, n0 = blockIdx.y * 128;
  f32x4 zero4 = {0.f, 0.f, 0.f, 0.f};
  f32x4 acc[4][4];
  #pragma unroll
  for (int mi = 0; mi < 4; ++mi)
    #pragma unroll
    for (int ni = 0; ni < 4; ++ni) acc[mi][ni] = zero4;
  gemm_core(xb, W, m0, n0, acc, As, Bs);
  int tid = threadIdx.x;
  int w = tid >> 6, lane = tid & 63, l15 = lane & 15, g = lane >> 4;
  int wr = w >> 1, wc = w & 1;
  #pragma unroll
  for (int mi = 0; mi < 4; ++mi)
    #pragma unroll
    for (int ni = 0; ni < 4; ++ni) {
      int e = n0 + wc * 64 + ni * 16 + l15;
      float bb = bias[e];
      int h = e >> 6, dd = e & 63;
      #pragma unroll
      for (int r = 0; r < 4; ++r) {
        int m = m0 + wr * 64 + mi * 16 + g * 4 + r;
        int b = m >> 11, s = m & 2047;
        unsigned short u = f2b(acc[mi][ni][r] + bb);
        int bh = b * H_ + h;
        if (z == 0)      Qb[((size_t)bh * S_ + s) * HD_ + dd] = u;
        else if (z == 1) Kb[((size_t)bh * S_ + s) * HD_ + dd] = u;
        else             Vtb[((size_t)bh * HD_ + dd) * S_ + s] = u;  // V transposed
      }
    }
}

// ---------------- output projection -> f32 tmp ----------------
__global__ __launch_bounds__(256) void gemm_proj(const unsigned short* __restrict__ AOb,
    const unsigned short* __restrict__ wob, const float* __restrict__ bo, float* __restrict__ Pf) {
  __shared__ unsigned short As[128 * 64], Bs[128 * 64];
  int m0 = blockIdx.x * 128, n0 = blockIdx.y * 128;
  f32x4 zero4 = {0.f, 0.f, 0.f, 0.f};
  f32x4 acc[4][4];
  #pragma unroll
  for (int mi = 0; mi < 4; ++mi)
    #pragma unroll
    for (int ni = 0; ni < 4; ++ni) acc[mi][ni] = zero4;
  gemm_core(AOb, wob, m0, n0, acc, As, Bs);
  int tid = threadIdx.x;
  int w = tid >> 6, lane = tid & 63, l15 = lane & 15, g = lane >> 4;
  int wr = w >> 1, wc = w & 1;
  #pragma unroll
  for (int mi = 0; mi < 4; ++mi)
    #pragma unroll
    for (int ni = 0; ni < 4; ++ni) {
      int e = n0 + wc * 64 + ni * 16 + l15;
      float bb = bo[e];
      #pragma unroll
      for (int r = 0; r < 4; ++r) {
        int m = m0 + wr * 64 + mi * 16 + g * 4 + r;
        Pf[(size_t)m * D_ + e] = acc[mi][ni][r] + bb;
      }
    }
}

// ---- flash attention: swapped QK^T 32x32x16, in-register P, cross-tile pipeline ----
// QKT(t+1) issued before softmax/PV(t): MFMA latency hides under softmax VALU.
__global__ __launch_bounds__(256, 2) void attn_kernel(const unsigned short* __restrict__ Qb,
    const unsigned short* __restrict__ Kb, const unsigned short* __restrict__ Vtb,
    const int* __restrict__ mask, const float* __restrict__ tptr,
    unsigned short* __restrict__ AOb) {
  __shared__ unsigned short Ks[3][64 * 64], Vs[3][64 * 64];
  int bh = blockIdx.y, b = bh >> 3, h = bh & 7;
  int tid = threadIdx.x, w = tid >> 6, lane = tid & 63;
  int l31 = lane & 31, hi = lane >> 5;
  float tl2 = tptr[0] * 1.44269504088896340736f;  // temp * log2(e)
  int q0w = blockIdx.x * 128 + w * 32;
  const unsigned short* Qbase = Qb + (size_t)bh * S_ * HD_;
  const int* mbase = mask + (size_t)b * S_;

  // Q as B-frag (32x32x16): lane n=l31=q, k=hi*8+j; qf[kk] covers d = kk*16 + hi*8 + j
  bf16x8 qf[4];
  #pragma unroll
  for (int kk = 0; kk < 4; ++kk)
    qf[kk] = *(const bf16x8*)&Qbase[(size_t)(q0w + l31) * HD_ + kk * 16 + hi * 8];

  bf16x8 ones;
  #pragma unroll
  for (int j = 0; j < 8; ++j) ones[j] = (__bf16)1.0f;

  f32x16 out[2], lacc, zc;
  #pragma unroll
  for (int i = 0; i < 16; ++i) { out[0][i] = 0.f; out[1][i] = 0.f; lacc[i] = 0.f; zc[i] = 0.f; }

  f32x16 stA[2], stB[2];

  #define STAGE_KV(buf, kb_) do {                                              \
    _Pragma("unroll")                                                          \
    for (int i = 0; i < 2; ++i) {                                              \
      int l = i * 256 + w * 64 + lane;                                         \
      int row = l >> 3, seg = l & 7;                                           \
      int sseg = seg ^ (row & 7);                                              \
      gload16(Kb + ((size_t)bh * S_ + (kb_) + row) * HD_ + sseg * 8,           \
              (char*)Ks[buf] + (size_t)(i * 256 + w * 64) * 16);               \
      gload16(Vtb + ((size_t)bh * HD_ + row) * S_ + (kb_) + sseg * 8,          \
              (char*)Vs[buf] + (size_t)(i * 256 + w * 64) * 16);               \
    }                                                                          \
  } while (0)

  #define QKT_TILE(KSBUF, ST) do {                                             \
    __builtin_amdgcn_s_setprio(1);                                             \
    const unsigned short* kbase_ = Ks[KSBUF];                                  \
    _Pragma("unroll")                                                          \
    for (int kk = 0; kk < 4; ++kk) {                                           \
      int sw = ((2 * kk + hi) ^ (l31 & 7)) * 8;                                \
      bf16x8 ka0 = *(const bf16x8*)&kbase_[l31 * 64 + sw];                     \
      bf16x8 ka1 = *(const bf16x8*)&kbase_[(32 + l31) * 64 + sw];              \
      ST[0] = __builtin_amdgcn_mfma_f32_32x32x16_bf16(ka0, qf[kk], kk ? ST[0] : zc, 0, 0, 0); \
      ST[1] = __builtin_amdgcn_mfma_f32_32x32x16_bf16(ka1, qf[kk], kk ? ST[1] : zc, 0, 0, 0); \
    }                                                                          \
    __builtin_amdgcn_s_setprio(0);                                             \
  } while (0)

  // BODY(T): barrier; stage T+2; QKT(T+1)->STN; softmax(STC); PV(T) with V[bPV].
  #define TILE_BODY(T, STC, STN, MV, bPV, bQK, bST) do {                       \
    __syncthreads();                                                           \
    unsigned long long bm = __ballot((MV) != 0);                               \
    if ((T) + 2 < 32) {                                                        \
      STAGE_KV(bST, ((T) + 2) * 64);                                           \
      MV = mbase[((T) + 2) * 64 + lane];                                       \
    }                                                                          \
    if ((T) + 1 < 32) QKT_TILE(bQK, STN);                                      \
    unsigned shlo = (unsigned)(bm >> (4 * hi));                                \
    unsigned shhi = (unsigned)(bm >> (32 + 4 * hi));                           \
    _Pragma("unroll")                                                          \
    for (int ktile = 0; ktile < 2; ++ktile)                                    \
      _Pragma("unroll")                                                        \
      for (int reg = 0; reg < 16; ++reg) {                                     \
        const int kc = 32 * ktile + (reg & 3) + 8 * (reg >> 2);                \
        float pv = exp2_hw(STC[ktile][reg] * tl2);                             \
        unsigned bit = ((kc < 32 ? shlo : shhi) >> (kc & 31)) & 1u;            \
        STC[ktile][reg] = bit ? 0.f : pv;                                      \
      }                                                                        \
    __builtin_amdgcn_s_setprio(1);                                             \
    const unsigned short* vbase_ = Vs[bPV];                                    \
    _Pragma("unroll")                                                          \
    for (int kp = 0; kp < 4; ++kp) {                                           \
      const int kt8 = kp >> 1;                                                 \
      const int ro = 8 * (kp & 1);                                             \
      unsigned Xa = cvtpk_bf16(STC[kt8][ro + 0], STC[kt8][ro + 1]);            \
      unsigned Ya = cvtpk_bf16(STC[kt8][ro + 4], STC[kt8][ro + 5]);            \
      unsigned Xb = cvtpk_bf16(STC[kt8][ro + 2], STC[kt8][ro + 3]);            \
      unsigned Yb = cvtpk_bf16(STC[kt8][ro + 6], STC[kt8][ro + 7]);            \
      plswap(Xa, Ya);                                                          \
      plswap(Xb, Yb);                                                          \
      union { unsigned u[4]; bf16x8 v; } pu;                                   \
      pu.u[0] = Xa; pu.u[1] = Xb; pu.u[2] = Ya; pu.u[3] = Yb;                  \
      bf16x8 pa = pu.v;                                                        \
      _Pragma("unroll")                                                        \
      for (int dn = 0; dn < 2; ++dn) {                                         \
        int row = dn * 32 + l31;                                               \
        bf16x8 vb = *(const bf16x8*)&vbase_[row * 64 + ((2 * kp + hi) ^ (row & 7)) * 8]; \
        out[dn] = __builtin_amdgcn_mfma_f32_32x32x16_bf16(pa, vb, out[dn], 0, 0, 0); \
      }                                                                        \
      lacc = __builtin_amdgcn_mfma_f32_32x32x16_bf16(pa, ones, lacc, 0, 0, 0); \
    }                                                                          \
    __builtin_amdgcn_s_setprio(0);                                             \
  } while (0)

  // prologue
  STAGE_KV(0, 0);
  int mvA = mbase[lane];
  __syncthreads();
  STAGE_KV(1, 64);
  int mvB = mbase[64 + lane];
  QKT_TILE(0, stA);

  int b0 = 0, b1 = 1, b2 = 2;
  for (int tp = 0; tp < 16; ++tp) {
    int t = 2 * tp;
    TILE_BODY(t, stA, stB, mvA, b0, b1, b2);
    TILE_BODY(t + 1, stB, stA, mvB, b1, b2, b0);
    int btmp = b0; b0 = b2; b2 = b1; b1 = btmp;   // (b0,b1,b2) <- (b2,b0,b1)
  }

  // ---- epilogue: out[q = q0w + crow][d = dn*32 + l31] / lsum[q] ----
  #pragma unroll
  for (int reg = 0; reg < 16; ++reg) {
    float inv = 1.f / lacc[reg];
    int q = q0w + (reg & 3) + 8 * (reg >> 2) + 4 * hi;
    #pragma unroll
    for (int dn = 0; dn < 2; ++dn)
      AOb[((size_t)b * S_ + q) * D_ + h * HD_ + dn * 32 + l31] = f2b(out[dn][reg] * inv);
  }
  #undef TILE_BODY
  #undef QKT_TILE
  #undef STAGE_KV
}

// ---------------- residual + LayerNorm ----------------
__global__ __launch_bounds__(256) void ln_kernel(const float* __restrict__ Pf,
    const float* __restrict__ x, const float* __restrict__ gamma,
    const float* __restrict__ beta, float* __restrict__ out) {
  int row = blockIdx.x * 4 + (threadIdx.x >> 6);
  int lane = threadIdx.x & 63;
  const float* pr = Pf + (size_t)row * D_;
  const float* xr = x + (size_t)row * D_;
  float4 a0 = *(const float4*)(pr + lane * 4);
  float4 a1 = *(const float4*)(pr + 256 + lane * 4);
  float4 b0 = *(const float4*)(xr + lane * 4);
  float4 b1 = *(const float4*)(xr + 256 + lane * 4);
  float y[8] = {a0.x + b0.x, a0.y + b0.y, a0.z + b0.z, a0.w + b0.w,
                a1.x + b1.x, a1.y + b1.y, a1.z + b1.z, a1.w + b1.w};
  float s = 0.f, s2 = 0.f;
  #pragma unroll
  for (int i = 0; i < 8; ++i) { s += y[i]; s2 += y[i] * y[i]; }
  #pragma unroll
  for (int d = 1; d < 64; d <<= 1) { s += __shfl_xor(s, d); s2 += __shfl_xor(s2, d); }
  float mu = s * (1.f / 512.f);
  float var = s2 * (1.f / 512.f) - mu * mu;
  float inv = rsqrtf(fmaxf(var, 0.f) + 1e-6f);
  float4 g0 = *(const float4*)(gamma + lane * 4);
  float4 g1 = *(const float4*)(gamma + 256 + lane * 4);
  float4 e0 = *(const float4*)(beta + lane * 4);
  float4 e1 = *(const float4*)(beta + 256 + lane * 4);
  float* orow = out + (size_t)row * D_;
  float4 o0 = {(y[0] - mu) * inv * g0.x + e0.x, (y[1] - mu) * inv * g0.y + e0.y,
               (y[2] - mu) * inv * g0.z + e0.z, (y[3] - mu) * inv * g0.w + e0.w};
  float4 o1 = {(y[4] - mu) * inv * g1.x + e1.x, (y[5] - mu) * inv * g1.y + e1.y,
               (y[6] - mu) * inv * g1.z + e1.z, (y[7] - mu) * inv * g1.w + e1.w};
  *(float4*)(orow + lane * 4) = o0;
  *(float4*)(orow + 256 + lane * 4) = o1;
}

extern "C" void kernel_launch(void* const* d_in, const int* in_sizes, int n_in,
                              void* d_out, int out_size, void* d_ws, size_t ws_size,
                              hipStream_t stream) {
  const float* x = (const float*)d_in[0];
  const int* mask = (const int*)d_in[1];
  const float* wq = (const float*)d_in[2];
  const float* bq = (const float*)d_in[3];
  const float* wk = (const float*)d_in[4];
  const float* bk = (const float*)d_in[5];
  const float* wv = (const float*)d_in[6];
  const float* bv = (const float*)d_in[7];
  const float* wo = (const float*)d_in[8];
  const float* bo = (const float*)d_in[9];
  const float* gamma = (const float*)d_in[10];
  const float* beta = (const float*)d_in[11];
  const float* temp = (const float*)d_in[12];
  float* out = (float*)d_out;
  char* ws = (char*)d_ws;
  const size_t MB = (size_t)1 << 20;
  unsigned short* xb  = (unsigned short*)(ws);                    // 8 MB
  unsigned short* wqb = (unsigned short*)(ws + 8 * MB);           // 0.5 MB
  unsigned short* wkb = (unsigned short*)(ws + 8 * MB + 512 * 1024);
  unsigned short* wvb = (unsigned short*)(ws + 9 * MB);
  unsigned short* wob = (unsigned short*)(ws + 9 * MB + 512 * 1024);
  unsigned short* Qb  = (unsigned short*)(ws + 10 * MB);          // 8 MB
  unsigned short* Kb  = (unsigned short*)(ws + 18 * MB);          // 8 MB
  float*          Pf  = (float*)(ws + 10 * MB);                   // 16 MB, overlays Q/K (used after attn)
  unsigned short* Vtb = (unsigned short*)(ws + 26 * MB);          // 8 MB
  unsigned short* AOb = (unsigned short*)(ws + 34 * MB);          // 8 MB

  cvt_all_kernel<<<(XN4 + 4 * WN4 + 255) / 256, 256, 0, stream>>>(
      x, wq, wk, wv, wo, xb, wqb, wkb, wvb, wob);
  gemm_qkv<<<dim3(64, 4, 3), 256, 0, stream>>>(xb, wqb, wkb, wvb, bq, bk, bv, Qb, Kb, Vtb);
  attn_kernel<<<dim3(16, 32), 256, 0, stream>>>(Qb, Kb, Vtb, mask, temp, AOb);
  gemm_proj<<<dim3(64, 4), 256, 0, stream>>>(AOb, wob, bo, Pf);
  ln_kernel<<<2048, 256, 0, stream>>>(Pf, x, gamma, beta, out);
}